// Round 3
// baseline (414.365 us; speedup 1.0000x reference)
//
#include <hip/hip_runtime.h>
#include <hip/hip_bf16.h>

#define B 2
#define H 32
#define S 2048
#define D 128

typedef __bf16 bf16x8 __attribute__((ext_vector_type(8)));
typedef float f32x4 __attribute__((ext_vector_type(4)));
typedef float f32x16 __attribute__((ext_vector_type(16)));

union BF8U { unsigned int u[4]; unsigned short s[8]; bf16x8 b; };

static constexpr float INV_SQRT_D = 0.08838834764831845f; // 1/sqrt(128)
static constexpr int NROWS = B * H * S; // 131072

__device__ __forceinline__ unsigned short bfbits(float f) {
    union { __bf16 h; unsigned short s; } cv;
    cv.h = (__bf16)f;  // native cvt (RNE); exact for small ints
    return cv.s;
}
__device__ __forceinline__ unsigned int pack2bf(float a, float b) {
    union { unsigned short s[2]; unsigned int u; } cv;
    cv.s[0] = bfbits(a); cv.s[1] = bfbits(b);
    return cv.u;
}

// ---------------- quantize K: row-major bf16 codes + per-row scale*1/sqrt(D)
__global__ __launch_bounds__(256) void quant_k_kernel(
    const float* __restrict__ x, unsigned short* __restrict__ qout,
    float* __restrict__ scl)
{
    const int row  = blockIdx.x * 4 + (threadIdx.x >> 6);
    const int lane = threadIdx.x & 63;
    const float2 v = *(const float2*)(x + (size_t)row * D + lane * 2);
    float m = fmaxf(fabsf(v.x), fabsf(v.y));
    #pragma unroll
    for (int off = 32; off; off >>= 1) m = fmaxf(m, __shfl_xor(m, off));
    const float scale = fmaxf(m / 127.0f, 1e-8f);
    const float q0 = fminf(fmaxf(rintf(v.x / scale), -127.0f), 127.0f);
    const float q1 = fminf(fmaxf(rintf(v.y / scale), -127.0f), 127.0f);
    *(unsigned int*)(qout + (size_t)row * D + lane * 2) = pack2bf(q0, q1);
    if (lane == 0) scl[row] = scale * INV_SQRT_D;
}

// ------------- quantize V: transposed [B,H,D,S] bf16 codes + scale ----------
__global__ __launch_bounds__(256) void quant_v_kernel(
    const float* __restrict__ x, unsigned short* __restrict__ vtq,
    float* __restrict__ scl)
{
    __shared__ __align__(16) unsigned short vt[D][72];
    const int bh = blockIdx.y;
    const int s0 = blockIdx.x * 64;
    const int wave = threadIdx.x >> 6, lane = threadIdx.x & 63;

    #pragma unroll 1
    for (int i = 0; i < 16; i++) {
        const int tok = wave * 16 + i;
        const float2 v = *(const float2*)(x + ((size_t)bh * S + s0 + tok) * D + lane * 2);
        float m = fmaxf(fabsf(v.x), fabsf(v.y));
        #pragma unroll
        for (int off = 32; off; off >>= 1) m = fmaxf(m, __shfl_xor(m, off));
        const float scale = fmaxf(m / 127.0f, 1e-8f);
        const float q0 = fminf(fmaxf(rintf(v.x / scale), -127.0f), 127.0f);
        const float q1 = fminf(fmaxf(rintf(v.y / scale), -127.0f), 127.0f);
        vt[lane * 2    ][tok] = bfbits(q0);
        vt[lane * 2 + 1][tok] = bfbits(q1);
        if (lane == 0) scl[(size_t)bh * S + s0 + tok] = scale;
    }
    __syncthreads();
    const int d = threadIdx.x >> 1, hf = (threadIdx.x & 1) * 32;
    unsigned short* dst = vtq + ((size_t)bh * D + d) * S + s0 + hf;
    #pragma unroll
    for (int i = 0; i < 4; i++)
        *(int4*)(dst + i * 8) = *(const int4*)&vt[d][hf + i * 8];
}

// --------------------------- flash attention --------------------------------
// 32x32x16 MFMA, swapped QK^T. 4 waves x 32 q-rows = 128 q per block.
// Softmax q = lane&31 lane-local; acc q spread over regs (verified C/D map).
__global__ __launch_bounds__(256, 3) void attn_kernel(
    const float* __restrict__ Q, const unsigned short* __restrict__ Kq,
    const float* __restrict__ Ks, const unsigned short* __restrict__ Vt,
    const float* __restrict__ Vs, float* __restrict__ Out)
{
    __shared__ __align__(16) unsigned short Klds[64][136];
    __shared__ __align__(16) unsigned short Vlds[D][72];
    __shared__ float KSs[64];
    __shared__ float VSs[64];

    const int bh = blockIdx.y;
    const int qt = blockIdx.x;           // 128-q tile index
    const int tid = threadIdx.x;
    const int wave = tid >> 6, lane = tid & 63;
    const int l31 = lane & 31, g2 = lane >> 5;
    const bool hi = (g2 != 0);

    // Q fragments (B operand): lane = col q = l31; k = g2*8+j per 16-chunk kk
    bf16x8 qf[8];
    {
        const float* qp = Q + ((size_t)bh * S + qt * 128 + wave * 32 + l31) * D + g2 * 8;
        #pragma unroll
        for (int kk = 0; kk < 8; kk++) {
            float4 a = *(const float4*)(qp + kk * 16);
            float4 b = *(const float4*)(qp + kk * 16 + 4);
            BF8U t;
            t.s[0] = bfbits(a.x); t.s[1] = bfbits(a.y); t.s[2] = bfbits(a.z); t.s[3] = bfbits(a.w);
            t.s[4] = bfbits(b.x); t.s[5] = bfbits(b.y); t.s[6] = bfbits(b.z); t.s[7] = bfbits(b.w);
            qf[kk] = t.b;
        }
    }

    f32x16 acc[4];
    #pragma unroll
    for (int n = 0; n < 4; n++)
        #pragma unroll
        for (int r = 0; r < 16; r++) acc[n][r] = 0.f;
    float mrun = -1e30f, lrun = 0.f;   // per-lane, q = l31 (dup over g2)

    const size_t kbase = (size_t)bh * S * D;
    const size_t vbase = (size_t)bh * D * S;

    for (int t = 0; t < S / 64; t++) {
        const int kv0 = t * 64;
        // stage K tile (64 x 128): contiguous lane->16B, bank-group rotates
        #pragma unroll
        for (int p = 0; p < 4; p++) {
            const int row = p * 16 + (tid >> 4);
            const int col = (tid & 15) * 8;
            *(int4*)&Klds[row][col] =
                *(const int4*)(Kq + kbase + (size_t)(kv0 + row) * D + col);
        }
        // stage V^T tile (128 x 64)
        #pragma unroll
        for (int p = 0; p < 4; p++) {
            const int d = p * 32 + (tid >> 3);
            const int col = (tid & 7) * 8;
            *(int4*)&Vlds[d][col] =
                *(const int4*)(Vt + vbase + (size_t)d * S + kv0 + col);
        }
        if (tid < 64)       KSs[tid]      = Ks[(size_t)bh * S + kv0 + tid];
        else if (tid < 128) VSs[tid - 64] = Vs[(size_t)bh * S + kv0 + tid - 64];
        __syncthreads();

        // QK^T swapped: sacc[n2] reg r = S[kv = 32n2+(r&3)+8(r>>2)+4g2][q=l31]
        f32x16 sacc[2];
        #pragma unroll
        for (int n2 = 0; n2 < 2; n2++) {
            #pragma unroll
            for (int r = 0; r < 16; r++) sacc[n2][r] = 0.f;
            #pragma unroll
            for (int kk = 0; kk < 8; kk++) {
                bf16x8 kf = *(const bf16x8*)&Klds[n2 * 32 + l31][kk * 16 + g2 * 8];
                sacc[n2] = __builtin_amdgcn_mfma_f32_32x32x16_bf16(kf, qf[kk], sacc[n2], 0, 0, 0);
            }
        }
        // scales: broadcast f32x4 (element r&3 <-> kv offset)
        float sv[2][16];
        float mx = -1e30f;
        #pragma unroll
        for (int n2 = 0; n2 < 2; n2++)
            #pragma unroll
            for (int rq = 0; rq < 4; rq++) {
                const f32x4 ks4 = *(const f32x4*)&KSs[n2 * 32 + rq * 8 + g2 * 4];
                #pragma unroll
                for (int j = 0; j < 4; j++) {
                    const float s = sacc[n2][rq * 4 + j] * ks4[j];
                    sv[n2][rq * 4 + j] = s;
                    mx = fmaxf(mx, s);
                }
            }
        mx = fmaxf(mx, __shfl_xor(mx, 32));

        // defer-max (T13): rescale only when max grew past threshold
        if (!__all(mx - mrun <= 8.0f)) {
            const float mnew = fmaxf(mrun, mx);
            const float corr = __expf(mrun - mnew);
            mrun = mnew;
            lrun *= corr;
            float cq[16];
            #pragma unroll
            for (int r = 0; r < 16; r++)
                cq[r] = __shfl(corr, (r & 3) + 8 * (r >> 2) + 4 * g2);
            #pragma unroll
            for (int n = 0; n < 4; n++)
                #pragma unroll
                for (int r = 0; r < 16; r++) acc[n][r] *= cq[r];
        }

        // P = exp(S - m), fold v-scale; psum
        float pv[2][16];
        float ps = 0.f;
        #pragma unroll
        for (int n2 = 0; n2 < 2; n2++)
            #pragma unroll
            for (int rq = 0; rq < 4; rq++) {
                const f32x4 vs4 = *(const f32x4*)&VSs[n2 * 32 + rq * 8 + g2 * 4];
                #pragma unroll
                for (int j = 0; j < 4; j++) {
                    const float p = __expf(sv[n2][rq * 4 + j] - mrun);
                    ps += p;
                    pv[n2][rq * 4 + j] = p * vs4[j];
                }
            }
        ps += __shfl_xor(ps, 32);
        lrun += ps;

        // pack P' pairs: word W holds kv pair base 32n2 + 8(W>>1)+2(W&1)+4g2
        unsigned int w0[8], w1[8], o0[8], o1[8];
        #pragma unroll
        for (int W = 0; W < 8; W++) {
            const int rA = 4 * (W >> 1) + 2 * (W & 1);
            w0[W] = pack2bf(pv[0][rA], pv[0][rA + 1]);
            w1[W] = pack2bf(pv[1][rA], pv[1][rA + 1]);
        }
        #pragma unroll
        for (int W = 0; W < 8; W++) {
            o0[W] = (unsigned int)__shfl_xor((int)w0[W], 32);
            o1[W] = (unsigned int)__shfl_xor((int)w1[W], 32);
        }

        // PV: A = P (row q=l31, k = kv 16kc+8g2+2j2+{0,1}), B = V^T
        #pragma unroll
        for (int kc = 0; kc < 4; kc++) {
            unsigned int pwv[4];
            #pragma unroll
            for (int j2 = 0; j2 < 4; j2++) {
                const int Wa = 4 * (kc & 1) + (j2 & 1);
                const int Wb = Wa + 2;
                unsigned int a, b;
                if (kc < 2) {
                    a = (j2 < 2) ? w0[Wa] : o0[Wa];
                    b = (j2 < 2) ? o0[Wb] : w0[Wb];
                } else {
                    a = (j2 < 2) ? w1[Wa] : o1[Wa];
                    b = (j2 < 2) ? o1[Wb] : w1[Wb];
                }
                pwv[j2] = hi ? b : a;
            }
            BF8U tt;
            tt.u[0] = pwv[0]; tt.u[1] = pwv[1]; tt.u[2] = pwv[2]; tt.u[3] = pwv[3];
            const bf16x8 pf = tt.b;
            #pragma unroll
            for (int nd = 0; nd < 4; nd++) {
                bf16x8 vf = *(const bf16x8*)&Vlds[nd * 32 + l31][kc * 16 + g2 * 8];
                acc[nd] = __builtin_amdgcn_mfma_f32_32x32x16_bf16(pf, vf, acc[nd], 0, 0, 0);
            }
        }
        __syncthreads();
    }

    // epilogue: gather per-row denom, store f32
    const float inv = 1.0f / lrun;
    float inv_q[16];
    #pragma unroll
    for (int r = 0; r < 16; r++)
        inv_q[r] = __shfl(inv, (r & 3) + 8 * (r >> 2) + 4 * g2);
    const size_t obase = ((size_t)bh * S + qt * 128 + wave * 32) * (size_t)D;
    #pragma unroll
    for (int r = 0; r < 16; r++) {
        const int q = (r & 3) + 8 * (r >> 2) + 4 * g2;
        #pragma unroll
        for (int nd = 0; nd < 4; nd++)
            Out[obase + (size_t)q * D + nd * 32 + l31] = acc[nd][r] * inv_q[r];
    }
}

extern "C" void kernel_launch(void* const* d_in, const int* in_sizes, int n_in,
                              void* d_out, int out_size, void* d_ws, size_t ws_size,
                              hipStream_t stream) {
    const float* q = (const float*)d_in[0];
    const float* k = (const float*)d_in[1];
    const float* v = (const float*)d_in[2];
    float* out = (float*)d_out;

    const size_t ELEMS = (size_t)NROWS * D; // 16777216
    unsigned short* kq  = (unsigned short*)d_ws;
    unsigned short* vtq = kq + ELEMS;
    float* ks = (float*)(vtq + ELEMS);
    float* vs = ks + NROWS;

    quant_k_kernel<<<NROWS / 4, 256, 0, stream>>>(k, kq, ks);
    quant_v_kernel<<<dim3(S / 64, B * H), 256, 0, stream>>>(v, vtq, vs);
    attn_kernel<<<dim3(S / 128, B * H), 256, 0, stream>>>(q, kq, ks, vtq, vs, out);
}